// Round 1
// baseline (229.629 us; speedup 1.0000x reference)
//
#include <hip/hip_runtime.h>
#include <type_traits>

namespace {
constexpr int HH = 512;
constexpr int WW = 512;
constexpr int KS = 11;
constexpr int PADR = 5;
constexpr int TH = 32;                 // tile rows per block
constexpr int TW = 64;                 // tile cols per block
constexpr int HC = TW + 2 * PADR;      // 74: columns incl. horizontal halo
constexpr int LP = 76;                 // LDS pitch: mult of 4 -> 16B-aligned rows
constexpr int NTHREADS = 256;
constexpr float SSIM_C1 = 1.0e-4f;     // (0.01*1.0)^2
constexpr float SSIM_C2 = 9.0e-4f;     // (0.03*1.0)^2
}

// One block per 32x64 output tile of one (b,c,t) plane.
// Phase 1: vertical 11-tap blur of {x, y, x^2, y^2, xy} at 32x74 positions
//          (incl. +-5 col halo), global reads served from L1 (24.9 KB/block
//          working set), results staged in LDS.
// Phase 2: horizontal 11-tap blur from LDS with 4-wide register blocking,
//          SSIM formula, float4 coalesced store.
__global__ __launch_bounds__(NTHREADS, 3) void ssim_fused(
    const float* __restrict__ x, const float* __restrict__ y,
    const float* __restrict__ kern, float* __restrict__ out)
{
    __shared__ __align__(16) float vb[5][TH][LP];

    constexpr int tiles_w = WW / TW;   // 8
    constexpr int tiles_h = HH / TH;   // 16
    constexpr int tpp = tiles_w * tiles_h;   // 128 tiles per plane

    const int bid = blockIdx.x;
    const int plane = bid / tpp;
    const int trem = bid - plane * tpp;
    const int tr_idx = trem / tiles_w;
    const int tile_r = tr_idx * TH;
    const int tile_c = (trem - tr_idx * tiles_w) * TW;

    const float* __restrict__ xp = x + (size_t)plane * (HH * WW);
    const float* __restrict__ yp = y + (size_t)plane * (HH * WW);
    float* __restrict__ op = out + (size_t)plane * (HH * WW);

    // 1D gaussian from the supplied 2D kernel (exact for outer-product kernels):
    // g[i] = k2d[5][i] / sqrt(k2d[5][5])
    float wt[KS];
    {
        const float c = kern[5 * KS + 5];
        const float inv = rsqrtf(c);
#pragma unroll
        for (int i = 0; i < KS; ++i) wt[i] = kern[5 * KS + i] * inv;
    }

    const int t = threadIdx.x;
    const bool interior = (tile_r >= PADR) && (tile_r + TH + PADR <= HH) &&
                          (tile_c >= PADR) && (tile_c + TW + PADR <= WW);

    auto phase1 = [&](auto intr_tag) {
        constexpr bool INTR = decltype(intr_tag)::value;
        for (int i = t; i < TH * HC; i += NTHREADS) {
            const int r = i / HC;
            const int c = i - r * HC;
            const int gr = tile_r + r;          // output row
            const int gc = tile_c + c - PADR;   // input col (may be OOB on border tiles)
            float sx = 0.f, sy = 0.f, sxx = 0.f, syy = 0.f, sxy = 0.f;
            if (INTR) {
                const float* xq = xp + (size_t)(gr - PADR) * WW + gc;
                const float* yq = yp + (size_t)(gr - PADR) * WW + gc;
#pragma unroll
                for (int k = 0; k < KS; ++k) {
                    const float xv = xq[(size_t)k * WW];
                    const float yv = yq[(size_t)k * WW];
                    const float w = wt[k];
                    sx  += w * xv;
                    sy  += w * yv;
                    sxx += w * xv * xv;
                    syy += w * yv * yv;
                    sxy += w * xv * yv;
                }
            } else {
                const bool cok = (gc >= 0) & (gc < WW);
#pragma unroll
                for (int k = 0; k < KS; ++k) {
                    const int rr = gr - PADR + k;
                    const bool ok = cok & (rr >= 0) & (rr < HH);
                    float xv = 0.f, yv = 0.f;
                    if (ok) {
                        xv = xp[(size_t)rr * WW + gc];
                        yv = yp[(size_t)rr * WW + gc];
                    }
                    const float w = wt[k];
                    sx  += w * xv;
                    sy  += w * yv;
                    sxx += w * xv * xv;
                    syy += w * yv * yv;
                    sxy += w * xv * yv;
                }
            }
            vb[0][r][c] = sx;
            vb[1][r][c] = sy;
            vb[2][r][c] = sxx;
            vb[3][r][c] = syy;
            vb[4][r][c] = sxy;
        }
    };

    if (interior) phase1(std::true_type{});
    else          phase1(std::false_type{});

    __syncthreads();

    // Phase 2: 512 groups of 4 horizontally-consecutive outputs; 2 groups/thread.
#pragma unroll
    for (int gi = 0; gi < (TH * (TW / 4)) / NTHREADS; ++gi) {
        const int g = t + gi * NTHREADS;
        const int r = g >> 4;              // / (TW/4)
        const int c0 = (g & 15) * 4;
        float res[5][4];
#pragma unroll
        for (int s = 0; s < 5; ++s) {
            float wnd[KS + 3];
#pragma unroll
            for (int i2 = 0; i2 < KS + 3; ++i2) wnd[i2] = vb[s][r][c0 + i2];
#pragma unroll
            for (int j = 0; j < 4; ++j) {
                float a = 0.f;
#pragma unroll
                for (int k = 0; k < KS; ++k) a += wt[k] * wnd[j + k];
                res[s][j] = a;
            }
        }
        float4 o;
#pragma unroll
        for (int j = 0; j < 4; ++j) {
            const float ux = res[0][j], uy = res[1][j];
            const float uxx = res[2][j], uyy = res[3][j], uxy = res[4][j];
            const float vx  = uxx - ux * ux;
            const float vy  = uyy - uy * uy;
            const float vxy = uxy - ux * uy;
            const float a1 = 2.f * ux * uy + SSIM_C1;
            const float a2 = 2.f * vxy + SSIM_C2;
            const float b1 = ux * ux + uy * uy + SSIM_C1;
            const float b2 = vx + vy + SSIM_C2;
            (&o.x)[j] = (a1 * a2) * __builtin_amdgcn_rcpf(b1 * b2);
        }
        *(float4*)(op + (size_t)(tile_r + r) * WW + (tile_c + c0)) = o;
    }
}

extern "C" void kernel_launch(void* const* d_in, const int* in_sizes, int n_in,
                              void* d_out, int out_size, void* d_ws, size_t ws_size,
                              hipStream_t stream) {
    const float* x    = (const float*)d_in[0];
    const float* y    = (const float*)d_in[1];
    const float* kern = (const float*)d_in[2];
    float* out = (float*)d_out;

    const int nplanes = in_sizes[0] / (HH * WW);            // 48
    const int nblocks = nplanes * (HH / TH) * (WW / TW);    // 6144

    ssim_fused<<<dim3(nblocks), dim3(NTHREADS), 0, stream>>>(x, y, kern, out);
}